// Round 16
// baseline (1328.588 us; speedup 1.0000x reference)
//
#include <hip/hip_runtime.h>
#include <math.h>

#define B_   32
#define L_   512
#define E_   300
#define H_   256
#define T_   4
#define NTOK 16384  // B*L
#define XGLD 2048   // 2 directions * 4H
#define SENT 2.0f   // impossible h value: |h| = |sigm*tanh| < 1

typedef float f32x4 __attribute__((ext_vector_type(4)));
typedef float f32x2 __attribute__((ext_vector_type(2)));

__device__ __forceinline__ float fsigmoid_(float x) { return 1.0f / (1.0f + __expf(-x)); }
__device__ __forceinline__ float ftanh_(float x) {
  return 1.0f - 2.0f / (__expf(2.0f * x) + 1.0f);   // exact limits at +-inf
}

// LLC-coherent (agent-scope) vector ops: sc0 sc1 bypass L1/L2 like relaxed
// agent atomics, but vectorized. Caller must s_waitcnt vmcnt before using loads.
__device__ __forceinline__ void llc_store_f32(float* p, float v) {
  asm volatile("global_store_dword %0, %1, off sc0 sc1" :: "v"(p), "v"(v) : "memory");
}
__device__ __forceinline__ void llc_store_f32x4(float* p, f32x4 v) {
  asm volatile("global_store_dwordx4 %0, %1, off sc0 sc1" :: "v"(p), "v"(v) : "memory");
}
__device__ __forceinline__ f32x4 llc_load_f32x4(const float* p) {
  f32x4 r;
  asm volatile("global_load_dwordx4 %0, %1, off sc0 sc1" : "=&v"(r) : "v"(p) : "memory");
  return r;
}

// ---------- stage A: xg[row][d*1024+g] = emb[wid[row]] . Wih_d[g] + b_d[g] ----------
// 128x128 block, 8x8 per-thread tile, register-prefetch software pipeline.
// Epilogue: grid-stride sentinel fill of h_all.
#define XBM 128
#define XBN 128
#define XBK 20
__global__ __launch_bounds__(256) void xproj_kernel(
    const int*   __restrict__ wid,    // [NTOK]
    const float* __restrict__ emb,    // [V][300]
    const float* __restrict__ wih_f,  // [1024][300]
    const float* __restrict__ wih_b,
    const float* __restrict__ b_f,
    const float* __restrict__ b_b,
    float* __restrict__ xg,           // [NTOK][2048]
    float*       h_all,               // sentinel-fill target
    int          n4)                  // h_all size in f32x4
{
  __shared__ float Ast[XBK][XBM];    // [k][m]  10 KB
  __shared__ float Bst[XBK][XBN];    // [k][n]  10 KB
  __shared__ int   wid_s[XBM];

  const int tid = threadIdx.x;
  const int m0 = blockIdx.y * XBM;
  const int n0 = blockIdx.x * XBN;   // 0..2047 in steps of 128
  const int d  = n0 >> 10;
  const float* wih  = d ? wih_b : wih_f;
  const float* bias = d ? b_b  : b_f;
  const int g0 = n0 & 1023;

  if (tid < XBM) wid_s[tid] = wid[m0 + tid];
  __syncthreads();

  const int srow = tid & 127;
  const int half = tid >> 7;         // wave-uniform
  const float* sbase = half ? (wih + (size_t)(g0 + srow) * E_)
                            : (emb + (size_t)wid_s[srow] * E_);
  float* sdst = half ? &Bst[0][0] : &Ast[0][0];

  f32x4 pre[5];
#pragma unroll
  for (int qd = 0; qd < 5; ++qd) pre[qd] = *(const f32x4*)(sbase + qd * 4);

  const int tx = tid & 15, ty = tid >> 4;
  float acc[8][8] = {};

  for (int k0 = 0; k0 < 300; k0 += XBK) {
#pragma unroll
    for (int qd = 0; qd < 5; ++qd)
#pragma unroll
      for (int e = 0; e < 4; ++e)
        sdst[(qd * 4 + e) * XBM + srow] = pre[qd][e];
    if (k0 + XBK < 300) {
      const float* p = sbase + k0 + XBK;
#pragma unroll
      for (int qd = 0; qd < 5; ++qd) pre[qd] = *(const f32x4*)(p + qd * 4);
    }
    __syncthreads();

#pragma unroll
    for (int k = 0; k < XBK; ++k) {
      float av[8], bv[8];
      *(f32x4*)&av[0] = *(const f32x4*)&Ast[k][ty * 8];
      *(f32x4*)&av[4] = *(const f32x4*)&Ast[k][ty * 8 + 4];
      *(f32x4*)&bv[0] = *(const f32x4*)&Bst[k][tx * 8];
      *(f32x4*)&bv[4] = *(const f32x4*)&Bst[k][tx * 8 + 4];
#pragma unroll
      for (int i = 0; i < 8; ++i)
#pragma unroll
        for (int j = 0; j < 8; ++j)
          acc[i][j] += av[i] * bv[j];
    }
    __syncthreads();
  }

#pragma unroll
  for (int i = 0; i < 8; ++i) {
    const int r = m0 + ty * 8 + i;
    float* op = xg + (size_t)r * XGLD + n0 + tx * 8;
#pragma unroll
    for (int j = 0; j < 8; ++j)
      op[j] = acc[i][j] + bias[g0 + tx * 8 + j];
  }

  {
    const int blin = blockIdx.y * 16 + blockIdx.x;   // 0..2047
    f32x4 sv = {SENT, SENT, SENT, SENT};
    for (int i = blin * 256 + tid; i < n4; i += 2048 * 256)
      llc_store_f32x4(h_all + (size_t)i * 4, sv);
  }
}

// ---------- stage B: LSTM, 256 blocks, role-split 3-slot schedule ----------
// Block = (d, q eighth of 4 batches, sl slice of 16 units). Phases A={0,1},B={2,3}.
//   slot1: GEMM_A(s)      [waves 0-3] || spin_B(s-1) [waves 5-6]
//   slot2: GEMM_B(s)      [waves 0-3] || reduce_A+pub [wave 4 lanes<32]
//   slot3: reduce_B+pub [wave4 >=32]  || spin_A(s)    [waves 5-6]
// GEMM worker: tid = kp*32 + bl*16 + u; holds all 4 gates' weights for unit u,
// k-chunk [32kp,+32) in 128 VGPRs; partial = f32x4 of gates. part_lds layout is
// lane-contiguous f32x4 -> conflict-free writes AND reads.
__global__ __launch_bounds__(512, 2) void lstm_kernel(
    const float* __restrict__ xg,     // [NTOK][2048]
    const float* __restrict__ whh_f,  // [1024][256]
    const float* __restrict__ whh_b,  // [1024][256]
    float*       h_all)               // [16 grp][512 t][4 bl][256 j]
{
  const int bid = blockIdx.x;        // 0..255
  const int d   = bid >> 7;
  const int q   = (bid >> 4) & 7;    // batch eighth
  const int sl  = bid & 15;          // slice
  const int tid = threadIdx.x;
  const float* __restrict__ whh = d ? whh_b : whh_f;

  __shared__ float h_lds[4 * 260];   // [bl][k+pad]  4.2 KB
  __shared__ f32x4 part_lds[2 * 256];// [ph][(kp*2+bl)*16+u]  8 KB

  // ---- GEMM worker identity + weights (waves 0-3) ----
  const int kp   = (tid >> 5) & 7;
  const int bl_g = (tid >> 4) & 1;
  const int u_g  = tid & 15;
  f32x4 wreg[4][8];
  if (tid < 256) {
#pragma unroll
    for (int gt = 0; gt < 4; ++gt) {
      const int grow = gt * 256 + sl * 16 + u_g;
      const float* rp = whh + (size_t)grow * H_ + kp * 32;
#pragma unroll
      for (int qq = 0; qq < 8; ++qq) wreg[gt][qq] = *(const f32x4*)(rp + qq * 4);
    }
  }

  for (int idx = tid; idx < 4 * 260; idx += 512) h_lds[idx] = 0.f;
  __syncthreads();

  float* hgrp = h_all + (size_t)(d * 8 + q) * (L_ * 1024);   // [512 t][4 bl][256 j]

  // ---- reduce identity (wave 4: tid 256..319) ----
  const int rlane   = tid - 256;           // 0..63 when wave 4
  const int r_u     = (rlane & 31) >> 1;
  const int r_bl_lo = rlane & 1;
  const int r_bl    = ((rlane >> 5) & 1) * 2 + r_bl_lo;   // lanes<32 -> A, >=32 -> B
  float c = 0.f;
  const float* xbase = xg + ((size_t)(q * 4 + r_bl) * L_) * XGLD + d * 1024 + sl * 16 + r_u;
  float x0 = 0.f, x1 = 0.f, x2 = 0.f, x3 = 0.f;
  if (tid >= 256 && tid < 320) {
    const int t0 = d ? (L_ - 1) : 0;
    const float* xp = xbase + (size_t)t0 * XGLD;
    x0 = xp[0]; x1 = xp[256]; x2 = xp[512]; x3 = xp[768];
  }

#define GEMM_PHASE(PH, BLBASE)                                                \
  do {                                                                        \
    const int blg = (BLBASE) + bl_g;                                          \
    const float* hb = &h_lds[blg * 260 + kp * 32];                            \
    f32x4 a = {0.f, 0.f, 0.f, 0.f};                                           \
    _Pragma("unroll")                                                         \
    for (int i = 0; i < 8; ++i) {                                             \
      f32x4 hv = *(const f32x4*)(hb + i * 4);                                 \
      a.x += wreg[0][i].x * hv.x + wreg[0][i].y * hv.y                        \
           + wreg[0][i].z * hv.z + wreg[0][i].w * hv.w;                       \
      a.y += wreg[1][i].x * hv.x + wreg[1][i].y * hv.y                        \
           + wreg[1][i].z * hv.z + wreg[1][i].w * hv.w;                       \
      a.z += wreg[2][i].x * hv.x + wreg[2][i].y * hv.y                        \
           + wreg[2][i].z * hv.z + wreg[2][i].w * hv.w;                       \
      a.w += wreg[3][i].x * hv.x + wreg[3][i].y * hv.y                        \
           + wreg[3][i].z * hv.z + wreg[3][i].w * hv.w;                       \
    }                                                                         \
    part_lds[(PH) * 256 + (kp * 2 + bl_g) * 16 + u_g] = a;                    \
  } while (0)

#define REDUCE_PUBLISH(PH, TT, TN)                                            \
  do {                                                                        \
    f32x4 g = {x0, x1, x2, x3};                                               \
    _Pragma("unroll")                                                         \
    for (int k2 = 0; k2 < 8; ++k2)                                            \
      g += part_lds[(PH) * 256 + (k2 * 2 + r_bl_lo) * 16 + r_u];              \
    float gi = fsigmoid_(g.x);                                                \
    float gf = fsigmoid_(g.y);                                                \
    float gg = ftanh_(g.z);                                                   \
    float go = fsigmoid_(g.w);                                                \
    c = gf * c + gi * gg;                                                     \
    float h = go * ftanh_(c);                                                 \
    llc_store_f32(&hgrp[(size_t)(TT) * 1024 + r_bl * 256 + sl * 16 + r_u], h);\
    if ((TN) >= 0) {                                                          \
      const float* xp = xbase + (size_t)(TN) * XGLD;                          \
      x0 = xp[0]; x1 = xp[256]; x2 = xp[512]; x3 = xp[768];                   \
    }                                                                         \
  } while (0)

#define SPIN_LOAD(BLBASE, TT)                                                 \
  do {                                                                        \
    const int i = tid - 320;                                                  \
    const int blg = (BLBASE) + (i >> 6);                                      \
    const int j4 = (i & 63) * 4;                                              \
    const float* p0 = hgrp + (size_t)(TT) * 1024 + blg * 256 + j4;            \
    f32x4 v0;                                                                 \
    bool bad;                                                                 \
    do {                                                                      \
      v0 = llc_load_f32x4(p0);                                                \
      asm volatile("s_waitcnt vmcnt(0)" ::: "memory");                        \
      __builtin_amdgcn_sched_barrier(0);                                      \
      bad = (v0.x == SENT) | (v0.y == SENT) | (v0.z == SENT) | (v0.w == SENT);\
    } while (bad);                                                            \
    *(f32x4*)&h_lds[blg * 260 + j4] = v0;                                     \
  } while (0)

  for (int s = 0; s < L_; ++s) {
    const int t  = d ? (L_ - 1 - s) : s;
    const int tp = d ? (t + 1) : (t - 1);          // previous step's time index
    const int tn = (s < L_ - 1) ? (d ? (t - 1) : (t + 1)) : -1;

    // ---- slot1: GEMM_A(s)  ||  spin_B(s-1) ----
    if (tid < 256) {
      GEMM_PHASE(0, 0);
    } else if (s > 0 && tid >= 320 && tid < 448) {
      SPIN_LOAD(2, tp);
    }
    __syncthreads();

    // ---- slot2: GEMM_B(s)  ||  reduce_A(s)+pub ----
    if (tid < 256) {
      GEMM_PHASE(1, 2);
    } else if (tid >= 256 && tid < 288) {
      REDUCE_PUBLISH(0, t, tn);
    }
    __syncthreads();

    // ---- slot3: reduce_B(s)+pub  ||  spin_A(s) ----
    if (tid >= 288 && tid < 320) {
      REDUCE_PUBLISH(1, t, tn);
    } else if (s < L_ - 1 && tid >= 320 && tid < 448) {
      SPIN_LOAD(0, t);
    }
    __syncthreads();
  }

#undef GEMM_PHASE
#undef REDUCE_PUBLISH
#undef SPIN_LOAD
}

// ---------- emissions: block = (t, q); em[b][t][tag] = bout + h_f.Wf + h_b.Wb ------
__global__ __launch_bounds__(256) void emis_kernel(
    const float* __restrict__ h_all,  // [16][512][4][256]
    const float* __restrict__ wout,   // [4][512]
    const float* __restrict__ bout,   // [4]
    float* __restrict__ em)           // [32][512][4]
{
  __shared__ float hf_l[1024];   // [bl][j]
  __shared__ float hb_l[1024];
  __shared__ float wsl[2048];

  const int t  = blockIdx.x >> 3;
  const int q  = blockIdx.x & 7;
  const int tid = threadIdx.x;
  const float* hfp = h_all + ((size_t)(0 + q) * L_ + t) * 1024;
  const float* hbp = h_all + ((size_t)(8 + q) * L_ + t) * 1024;

  if (tid < 256) {
    *(f32x4*)&hf_l[tid * 4] = *(const f32x4*)&hfp[tid * 4];
    *(f32x4*)&hb_l[tid * 4] = *(const f32x4*)&hbp[tid * 4];
  }
  for (int i = tid; i < 2048; i += 256) wsl[i] = wout[i];
  __syncthreads();

  const int bl = tid >> 6, lane = tid & 63;
  float s0 = 0.f, s1 = 0.f, s2 = 0.f, s3 = 0.f;
#pragma unroll
  for (int i = 0; i < 4; ++i) {
    const int j = i * 64 + lane;
    const float hfv = hf_l[bl * 256 + j], hbv = hb_l[bl * 256 + j];
    s0 += hfv * wsl[0 * 512 + j] + hbv * wsl[0 * 512 + 256 + j];
    s1 += hfv * wsl[1 * 512 + j] + hbv * wsl[1 * 512 + 256 + j];
    s2 += hfv * wsl[2 * 512 + j] + hbv * wsl[2 * 512 + 256 + j];
    s3 += hfv * wsl[3 * 512 + j] + hbv * wsl[3 * 512 + 256 + j];
  }
#pragma unroll
  for (int m = 1; m < 64; m <<= 1) {
    s0 += __shfl_xor(s0, m, 64);
    s1 += __shfl_xor(s1, m, 64);
    s2 += __shfl_xor(s2, m, 64);
    s3 += __shfl_xor(s3, m, 64);
  }
  if (lane == 0) {
    float* ep = em + ((size_t)(q * 4 + bl) * L_ + t) * 4;
    ep[0] = s0 + bout[0]; ep[1] = s1 + bout[1];
    ep[2] = s2 + bout[2]; ep[3] = s3 + bout[3];
  }
}

// ---------- Viterbi decode: one block per batch, em/hist staged in LDS ----------
__global__ __launch_bounds__(64) void viterbi_kernel(
    const float* __restrict__ em,      // [32][512][4]  (bias included)
    const float* __restrict__ trans,   // [4][4]
    const float* __restrict__ strans,  // [4]
    const float* __restrict__ etrans,  // [4]
    const int*   __restrict__ mask,    // [32][512]
    int* __restrict__ out)             // [32][512]
{
  __shared__ float em_l[512 * 4];
  __shared__ int   msk_l[512];
  __shared__ int   hist_l[512 * 4];
  __shared__ int   tags_l[512];

  const int b = blockIdx.x;
  const int tid = threadIdx.x;
  const float* ep = em + (size_t)b * L_ * 4;

  for (int i = tid; i < 512; i += 64) {
    *(f32x4*)&em_l[i * 4] = *(const f32x4*)&ep[i * 4];
    msk_l[i] = mask[b * L_ + i];
  }
  __syncthreads();

  if (tid == 0) {
    float tr[4][4];
#pragma unroll
    for (int i = 0; i < 4; ++i)
#pragma unroll
      for (int jj = 0; jj < 4; ++jj) tr[i][jj] = trans[i * 4 + jj];

    float sc[4];
#pragma unroll
    for (int tag = 0; tag < 4; ++tag) sc[tag] = strans[tag] + em_l[tag];

    for (int t = 1; t < L_; ++t) {
      float ns[4];
#pragma unroll
      for (int to = 0; to < 4; ++to) {
        float best = sc[0] + tr[0][to];
        int bf = 0;
#pragma unroll
        for (int fr = 1; fr < 4; ++fr) {
          float v = sc[fr] + tr[fr][to];
          if (v > best) { best = v; bf = fr; }
        }
        ns[to] = best + em_l[t * 4 + to];
        hist_l[t * 4 + to] = bf;
      }
      const int mt = msk_l[t];
#pragma unroll
      for (int to = 0; to < 4; ++to) sc[to] = mt ? ns[to] : sc[to];
    }

#pragma unroll
    for (int tag = 0; tag < 4; ++tag) sc[tag] += etrans[tag];
    int cur = 0;
    float best = sc[0];
#pragma unroll
    for (int i = 1; i < 4; ++i)
      if (sc[i] > best) { best = sc[i]; cur = i; }

    tags_l[L_ - 1] = msk_l[L_ - 1] ? cur : 0;
    for (int t = L_ - 1; t >= 1; --t) {
      if (msk_l[t]) cur = hist_l[t * 4 + cur];
      tags_l[t - 1] = msk_l[t - 1] ? cur : 0;
    }
  }
  __syncthreads();
  for (int i = tid; i < 512; i += 64) out[b * L_ + i] = tags_l[i];
}

extern "C" void kernel_launch(void* const* d_in, const int* in_sizes, int n_in,
                              void* d_out, int out_size, void* d_ws, size_t ws_size,
                              hipStream_t stream) {
  const int*   word_ids = (const int*)d_in[0];
  const int*   mask     = (const int*)d_in[1];
  // d_in[2] label_ids: unused
  const float* emb   = (const float*)d_in[3];
  const float* Wih_f = (const float*)d_in[4];
  const float* Whh_f = (const float*)d_in[5];
  const float* b_f   = (const float*)d_in[6];
  const float* Wih_b = (const float*)d_in[7];
  const float* Whh_b = (const float*)d_in[8];
  const float* b_b   = (const float*)d_in[9];
  const float* W_out = (const float*)d_in[10];
  const float* b_out = (const float*)d_in[11];
  const float* trans = (const float*)d_in[12];
  const float* strans = (const float*)d_in[13];
  const float* etrans = (const float*)d_in[14];
  int* out = (int*)d_out;

  float* xg    = (float*)d_ws;                             // 128 MiB
  float* h_all = xg + (size_t)NTOK * XGLD;                 // 16*512*1024 f32 = 33.5 MB
  float* em    = h_all + (size_t)16 * L_ * 1024;           // 256 KiB

  const int n4 = 16 * L_ * 1024 / 4;                       // 2,097,152 f32x4
  xproj_kernel<<<dim3(16, 128), 256, 0, stream>>>(word_ids, emb, Wih_f, Wih_b,
                                                  b_f, b_b, xg, h_all, n4);
  lstm_kernel<<<256, 512, 0, stream>>>(xg, Whh_f, Whh_b, h_all);
  emis_kernel<<<4096, 256, 0, stream>>>(h_all, W_out, b_out, em);
  viterbi_kernel<<<32, 64, 0, stream>>>(em, trans, strans, etrans, mask, out);
}

// Round 17
// 1098.870 us; speedup vs baseline: 1.2090x; 1.2090x over previous
//
#include <hip/hip_runtime.h>
#include <math.h>

#define B_   32
#define L_   512
#define E_   300
#define H_   256
#define T_   4
#define NTOK 16384  // B*L
#define XGLD 2048   // 2 directions * 4H
#define SENT 2.0f   // impossible h value: |h| = |sigm*tanh| < 1

typedef float f32x4 __attribute__((ext_vector_type(4)));
typedef float f32x2 __attribute__((ext_vector_type(2)));

__device__ __forceinline__ float fsigmoid_(float x) { return 1.0f / (1.0f + __expf(-x)); }
__device__ __forceinline__ float ftanh_(float x) {
  return 1.0f - 2.0f / (__expf(2.0f * x) + 1.0f);   // exact limits at +-inf
}

// LLC-coherent (agent-scope) vector ops: sc0 sc1 bypass L1/L2 like relaxed
// agent atomics, but vectorized. Caller must s_waitcnt vmcnt before using loads.
__device__ __forceinline__ void llc_store_f32(float* p, float v) {
  asm volatile("global_store_dword %0, %1, off sc0 sc1" :: "v"(p), "v"(v) : "memory");
}
__device__ __forceinline__ void llc_store_f32x4(float* p, f32x4 v) {
  asm volatile("global_store_dwordx4 %0, %1, off sc0 sc1" :: "v"(p), "v"(v) : "memory");
}
__device__ __forceinline__ f32x4 llc_load_f32x4(const float* p) {
  f32x4 r;
  asm volatile("global_load_dwordx4 %0, %1, off sc0 sc1" : "=&v"(r) : "v"(p) : "memory");
  return r;
}

// ---------- stage A: xg[row][d*1024+g] = emb[wid[row]] . Wih_d[g] + b_d[g] ----------
// 128x128 block, 8x8 per-thread tile, register-prefetch software pipeline.
// Epilogue: grid-stride sentinel fill of h_all.
#define XBM 128
#define XBN 128
#define XBK 20
__global__ __launch_bounds__(256) void xproj_kernel(
    const int*   __restrict__ wid,    // [NTOK]
    const float* __restrict__ emb,    // [V][300]
    const float* __restrict__ wih_f,  // [1024][300]
    const float* __restrict__ wih_b,
    const float* __restrict__ b_f,
    const float* __restrict__ b_b,
    float* __restrict__ xg,           // [NTOK][2048]
    float*       h_all,               // sentinel-fill target
    int          n4)                  // h_all size in f32x4
{
  __shared__ float Ast[XBK][XBM];    // [k][m]  10 KB
  __shared__ float Bst[XBK][XBN];    // [k][n]  10 KB
  __shared__ int   wid_s[XBM];

  const int tid = threadIdx.x;
  const int m0 = blockIdx.y * XBM;
  const int n0 = blockIdx.x * XBN;   // 0..2047 in steps of 128
  const int d  = n0 >> 10;
  const float* wih  = d ? wih_b : wih_f;
  const float* bias = d ? b_b  : b_f;
  const int g0 = n0 & 1023;

  if (tid < XBM) wid_s[tid] = wid[m0 + tid];
  __syncthreads();

  const int srow = tid & 127;
  const int half = tid >> 7;         // wave-uniform
  const float* sbase = half ? (wih + (size_t)(g0 + srow) * E_)
                            : (emb + (size_t)wid_s[srow] * E_);
  float* sdst = half ? &Bst[0][0] : &Ast[0][0];

  f32x4 pre[5];
#pragma unroll
  for (int qd = 0; qd < 5; ++qd) pre[qd] = *(const f32x4*)(sbase + qd * 4);

  const int tx = tid & 15, ty = tid >> 4;
  float acc[8][8] = {};

  for (int k0 = 0; k0 < 300; k0 += XBK) {
#pragma unroll
    for (int qd = 0; qd < 5; ++qd)
#pragma unroll
      for (int e = 0; e < 4; ++e)
        sdst[(qd * 4 + e) * XBM + srow] = pre[qd][e];
    if (k0 + XBK < 300) {
      const float* p = sbase + k0 + XBK;
#pragma unroll
      for (int qd = 0; qd < 5; ++qd) pre[qd] = *(const f32x4*)(p + qd * 4);
    }
    __syncthreads();

#pragma unroll
    for (int k = 0; k < XBK; ++k) {
      float av[8], bv[8];
      *(f32x4*)&av[0] = *(const f32x4*)&Ast[k][ty * 8];
      *(f32x4*)&av[4] = *(const f32x4*)&Ast[k][ty * 8 + 4];
      *(f32x4*)&bv[0] = *(const f32x4*)&Bst[k][tx * 8];
      *(f32x4*)&bv[4] = *(const f32x4*)&Bst[k][tx * 8 + 4];
#pragma unroll
      for (int i = 0; i < 8; ++i)
#pragma unroll
        for (int j = 0; j < 8; ++j)
          acc[i][j] += av[i] * bv[j];
    }
    __syncthreads();
  }

#pragma unroll
  for (int i = 0; i < 8; ++i) {
    const int r = m0 + ty * 8 + i;
    float* op = xg + (size_t)r * XGLD + n0 + tx * 8;
#pragma unroll
    for (int j = 0; j < 8; ++j)
      op[j] = acc[i][j] + bias[g0 + tx * 8 + j];
  }

  {
    const int blin = blockIdx.y * 16 + blockIdx.x;   // 0..2047
    f32x4 sv = {SENT, SENT, SENT, SENT};
    for (int i = blin * 256 + tid; i < n4; i += 2048 * 256)
      llc_store_f32x4(h_all + (size_t)i * 4, sv);
  }
}

// ---------- stage B: LSTM, 256 blocks, 2-phase batch pipeline (round-12 proven) -----
// Block = (d, q eighth of 4 batches, sl slice of 16 units = 64 gate rows, unit-major).
// Phases: A = batches {0,1}, B = {2,3}. 4-slot schedule per step:
//   slot1 GEMM_A(s) | slot2 reduce_A(s)+pub || spin_B(s-1) | slot3 GEMM_B(s) |
//   slot4 reduce_B(s)+pub || spin_A(s)
__global__ __launch_bounds__(512, 2) void lstm_kernel(
    const float* __restrict__ xg,     // [NTOK][2048]
    const float* __restrict__ whh_f,  // [1024][256]
    const float* __restrict__ whh_b,  // [1024][256]
    float*       h_all)               // [16 grp][512 t][4 bl][256 j]
{
  const int bid = blockIdx.x;        // 0..255
  const int d   = bid >> 7;
  const int q   = (bid >> 4) & 7;    // batch eighth
  const int sl  = bid & 15;          // slice
  const int tid = threadIdx.x;
  const int kp  = tid >> 6;          // 0..7 (wave / k-chunk)
  const int lane = tid & 63;
  const int bl_loc = lane >> 5;      // batch within phase (0/1)
  const int rg  = lane & 31;         // row pair index
  const float* __restrict__ whh = d ? whh_b : whh_f;

  __shared__ float h_lds[4 * 260];           // h[bl][k+pad]             (4.2 KB)
  __shared__ float part_lds[2 * 8 * 2 * 72]; // [ph][kp][bl_loc][row+pad] (9.2 KB)

  // ---- per-thread weights: rows rg*2, rg*2+1 (unit-major), k-chunk kp ----
  f32x4 wreg[2][8];
#pragma unroll
  for (int r = 0; r < 2; ++r) {
    const int row_l = rg * 2 + r;            // u*4 + gt
    const int u  = row_l >> 2;
    const int gt = row_l & 3;
    const int grow = gt * 256 + sl * 16 + u;
    const float* rp = whh + (size_t)grow * H_ + kp * 32;
#pragma unroll
    for (int qq = 0; qq < 8; ++qq) wreg[r][qq] = *(const f32x4*)(rp + qq * 4);
  }

  for (int idx = tid; idx < 4 * 260; idx += 512) h_lds[idx] = 0.f;
  __syncthreads();

  float* hgrp = h_all + (size_t)(d * 8 + q) * (L_ * 1024);   // [512 t][4 bl][256 j]

  // reduce-thread state: tid<32 -> phase A (bl 0,1); tid 32..63 -> phase B (bl 2,3)
  const int r_u  = (tid & 31) >> 1;
  const int r_bl = (tid < 32) ? (tid & 1) : (2 + (tid & 1));
  float c = 0.f;
  const float* xbase = xg + ((size_t)(q * 4 + r_bl) * L_) * XGLD + d * 1024 + sl * 16 + r_u;
  float x0 = 0.f, x1 = 0.f, x2 = 0.f, x3 = 0.f;
  if (tid < 64) {
    const int t0 = d ? (L_ - 1) : 0;
    const float* xp = xbase + (size_t)t0 * XGLD;
    x0 = xp[0]; x1 = xp[256]; x2 = xp[512]; x3 = xp[768];
  }

#define GEMM_PHASE(PH, BLBASE)                                                \
  do {                                                                        \
    const int blg = (BLBASE) + bl_loc;                                        \
    const float* hb = &h_lds[blg * 260 + kp * 32];                            \
    float a0 = 0.f, a1 = 0.f;                                                 \
    _Pragma("unroll")                                                         \
    for (int i = 0; i < 8; ++i) {                                             \
      f32x4 hv = *(const f32x4*)(hb + i * 4);                                 \
      a0 += wreg[0][i].x * hv.x + wreg[0][i].y * hv.y                         \
          + wreg[0][i].z * hv.z + wreg[0][i].w * hv.w;                        \
      a1 += wreg[1][i].x * hv.x + wreg[1][i].y * hv.y                         \
          + wreg[1][i].z * hv.z + wreg[1][i].w * hv.w;                        \
    }                                                                         \
    f32x2 pv = {a0, a1};                                                      \
    *(f32x2*)&part_lds[(PH) * 1152 + kp * 144 + bl_loc * 72 + rg * 2] = pv;   \
  } while (0)

#define REDUCE_PUBLISH(PH, TT, TN)                                            \
  do {                                                                        \
    f32x4 g = {x0, x1, x2, x3};                                               \
    _Pragma("unroll")                                                         \
    for (int k2 = 0; k2 < 8; ++k2)                                            \
      g += *(const f32x4*)&part_lds[(PH) * 1152 + k2 * 144                    \
                                    + (tid & 1) * 72 + r_u * 4];              \
    float gi = fsigmoid_(g.x);                                                \
    float gf = fsigmoid_(g.y);                                                \
    float gg = ftanh_(g.z);                                                   \
    float go = fsigmoid_(g.w);                                                \
    c = gf * c + gi * gg;                                                     \
    float h = go * ftanh_(c);                                                 \
    llc_store_f32(&hgrp[(size_t)(TT) * 1024 + r_bl * 256 + sl * 16 + r_u], h);\
    if ((TN) >= 0) {                                                          \
      const float* xp = xbase + (size_t)(TN) * XGLD;                          \
      x0 = xp[0]; x1 = xp[256]; x2 = xp[512]; x3 = xp[768];                   \
    }                                                                         \
  } while (0)

#define SPIN_LOAD(BLBASE, TT)                                                 \
  do {                                                                        \
    const int i = tid - 64;                                                   \
    const int blg = (BLBASE) + (i >> 6);                                      \
    const int j4 = (i & 63) * 4;                                              \
    const float* p0 = hgrp + (size_t)(TT) * 1024 + blg * 256 + j4;            \
    f32x4 v0;                                                                 \
    bool bad;                                                                 \
    do {                                                                      \
      v0 = llc_load_f32x4(p0);                                                \
      asm volatile("s_waitcnt vmcnt(0)" ::: "memory");                        \
      __builtin_amdgcn_sched_barrier(0);                                      \
      bad = (v0.x == SENT) | (v0.y == SENT) | (v0.z == SENT) | (v0.w == SENT);\
    } while (bad);                                                            \
    *(f32x4*)&h_lds[blg * 260 + j4] = v0;                                     \
  } while (0)

  for (int s = 0; s < L_; ++s) {
    const int t  = d ? (L_ - 1 - s) : s;
    const int tp = d ? (t + 1) : (t - 1);          // previous step's time index
    const int tn = (s < L_ - 1) ? (d ? (t - 1) : (t + 1)) : -1;

    // ---- slot1: GEMM phase A ----
    GEMM_PHASE(0, 0);
    __syncthreads();

    // ---- slot2: reduce/publish A(s)  ||  spin B(s-1) ----
    if (tid < 32) {
      REDUCE_PUBLISH(0, t, tn);
    } else if (s > 0 && tid >= 64 && tid < 192) {
      SPIN_LOAD(2, tp);
    }
    __syncthreads();

    // ---- slot3: GEMM phase B ----
    GEMM_PHASE(1, 2);
    __syncthreads();

    // ---- slot4: reduce/publish B(s)  ||  spin A(s) ----
    if (tid >= 32 && tid < 64) {
      REDUCE_PUBLISH(1, t, tn);
    } else if (s < L_ - 1 && tid >= 64 && tid < 192) {
      SPIN_LOAD(0, t);
    }
    __syncthreads();
  }

#undef GEMM_PHASE
#undef REDUCE_PUBLISH
#undef SPIN_LOAD
}

// ---------- fused emissions + Viterbi: one block per batch ----------
// 512 threads: 8 waves each compute em[t][0..4) for 64 t values (coalesced h_all
// reads + shfl reduce), staged to LDS; then thread 0 runs the Viterbi recurrence
// entirely in LDS and the block writes the tag sequence.
__global__ __launch_bounds__(512) void emvit_kernel(
    const float* __restrict__ h_all,   // [16][512][4][256]
    const float* __restrict__ wout,    // [4][512]
    const float* __restrict__ bout,    // [4]
    const float* __restrict__ trans,   // [4][4]
    const float* __restrict__ strans,  // [4]
    const float* __restrict__ etrans,  // [4]
    const int*   __restrict__ mask,    // [32][512]
    int* __restrict__ out)             // [32][512]
{
  __shared__ float em_l[512 * 4];
  __shared__ float wsl[2048];
  __shared__ int   msk_l[512];
  __shared__ int   hist_l[512 * 4];
  __shared__ int   tags_l[512];

  const int b = blockIdx.x;
  const int q = b >> 2, blq = b & 3;
  const int tid = threadIdx.x;
  const float* hfp = h_all + (size_t)(0 + q) * (L_ * 1024) + blq * 256;
  const float* hbp = h_all + (size_t)(8 + q) * (L_ * 1024) + blq * 256;

  for (int i = tid; i < 2048; i += 512) wsl[i] = wout[i];
  if (tid < 512) msk_l[tid] = mask[b * L_ + tid];
  __syncthreads();

  const int tw = tid >> 6, lane = tid & 63;
  const float bo0 = bout[0], bo1 = bout[1], bo2 = bout[2], bo3 = bout[3];
  for (int tt = tw; tt < L_; tt += 8) {
    const float* hf = hfp + (size_t)tt * 1024;
    const float* hb = hbp + (size_t)tt * 1024;
    float s0 = 0.f, s1 = 0.f, s2 = 0.f, s3 = 0.f;
#pragma unroll
    for (int i = 0; i < 4; ++i) {
      const int j = i * 64 + lane;
      const float hfv = hf[j], hbv = hb[j];
      s0 += hfv * wsl[j]        + hbv * wsl[256 + j];
      s1 += hfv * wsl[512 + j]  + hbv * wsl[768 + j];
      s2 += hfv * wsl[1024 + j] + hbv * wsl[1280 + j];
      s3 += hfv * wsl[1536 + j] + hbv * wsl[1792 + j];
    }
#pragma unroll
    for (int m = 1; m < 64; m <<= 1) {
      s0 += __shfl_xor(s0, m, 64);
      s1 += __shfl_xor(s1, m, 64);
      s2 += __shfl_xor(s2, m, 64);
      s3 += __shfl_xor(s3, m, 64);
    }
    if (lane == 0) {
      em_l[tt * 4 + 0] = s0 + bo0;
      em_l[tt * 4 + 1] = s1 + bo1;
      em_l[tt * 4 + 2] = s2 + bo2;
      em_l[tt * 4 + 3] = s3 + bo3;
    }
  }
  __syncthreads();

  if (tid == 0) {
    float tr[4][4];
#pragma unroll
    for (int i = 0; i < 4; ++i)
#pragma unroll
      for (int jj = 0; jj < 4; ++jj) tr[i][jj] = trans[i * 4 + jj];

    float sc[4];
#pragma unroll
    for (int tag = 0; tag < 4; ++tag) sc[tag] = strans[tag] + em_l[tag];

    for (int t = 1; t < L_; ++t) {
      float ns[4];
#pragma unroll
      for (int to = 0; to < 4; ++to) {
        float best = sc[0] + tr[0][to];
        int bf = 0;
#pragma unroll
        for (int fr = 1; fr < 4; ++fr) {
          float v = sc[fr] + tr[fr][to];
          if (v > best) { best = v; bf = fr; }
        }
        ns[to] = best + em_l[t * 4 + to];
        hist_l[t * 4 + to] = bf;
      }
      const int mt = msk_l[t];
#pragma unroll
      for (int to = 0; to < 4; ++to) sc[to] = mt ? ns[to] : sc[to];
    }

#pragma unroll
    for (int tag = 0; tag < 4; ++tag) sc[tag] += etrans[tag];
    int cur = 0;
    float best = sc[0];
#pragma unroll
    for (int i = 1; i < 4; ++i)
      if (sc[i] > best) { best = sc[i]; cur = i; }

    tags_l[L_ - 1] = msk_l[L_ - 1] ? cur : 0;
    for (int t = L_ - 1; t >= 1; --t) {
      if (msk_l[t]) cur = hist_l[t * 4 + cur];
      tags_l[t - 1] = msk_l[t - 1] ? cur : 0;
    }
  }
  __syncthreads();
  if (tid < 512) out[b * L_ + tid] = tags_l[tid];
}

extern "C" void kernel_launch(void* const* d_in, const int* in_sizes, int n_in,
                              void* d_out, int out_size, void* d_ws, size_t ws_size,
                              hipStream_t stream) {
  const int*   word_ids = (const int*)d_in[0];
  const int*   mask     = (const int*)d_in[1];
  // d_in[2] label_ids: unused
  const float* emb   = (const float*)d_in[3];
  const float* Wih_f = (const float*)d_in[4];
  const float* Whh_f = (const float*)d_in[5];
  const float* b_f   = (const float*)d_in[6];
  const float* Wih_b = (const float*)d_in[7];
  const float* Whh_b = (const float*)d_in[8];
  const float* b_b   = (const float*)d_in[9];
  const float* W_out = (const float*)d_in[10];
  const float* b_out = (const float*)d_in[11];
  const float* trans = (const float*)d_in[12];
  const float* strans = (const float*)d_in[13];
  const float* etrans = (const float*)d_in[14];
  int* out = (int*)d_out;

  float* xg    = (float*)d_ws;                             // 128 MiB
  float* h_all = xg + (size_t)NTOK * XGLD;                 // 16*512*1024 f32 = 33.5 MB

  const int n4 = 16 * L_ * 1024 / 4;                       // 2,097,152 f32x4
  xproj_kernel<<<dim3(16, 128), 256, 0, stream>>>(word_ids, emb, Wih_f, Wih_b,
                                                  b_f, b_b, xg, h_all, n4);
  lstm_kernel<<<256, 512, 0, stream>>>(xg, Whh_f, Whh_b, h_all);
  emvit_kernel<<<32, 512, 0, stream>>>(h_all, W_out, b_out, trans, strans,
                                       etrans, mask, out);
}

// Round 18
// 1046.470 us; speedup vs baseline: 1.2696x; 1.0501x over previous
//
#include <hip/hip_runtime.h>
#include <math.h>

#define B_   32
#define L_   512
#define E_   300
#define H_   256
#define T_   4
#define NTOK 16384  // B*L
#define XGLD 2048   // 2 directions * 4H
#define SENT 2.0f   // impossible h value: |h| = |sigm*tanh| < 1

typedef float f32x4 __attribute__((ext_vector_type(4)));
typedef float f32x2 __attribute__((ext_vector_type(2)));

__device__ __forceinline__ float fsigmoid_(float x) { return 1.0f / (1.0f + __expf(-x)); }
__device__ __forceinline__ float ftanh_(float x) {
  return 1.0f - 2.0f / (__expf(2.0f * x) + 1.0f);   // exact limits at +-inf
}

// LLC-coherent (agent-scope) vector ops: sc0 sc1 bypass L1/L2 like relaxed
// agent atomics, but vectorized. Caller must s_waitcnt vmcnt before using loads.
__device__ __forceinline__ void llc_store_f32(float* p, float v) {
  asm volatile("global_store_dword %0, %1, off sc0 sc1" :: "v"(p), "v"(v) : "memory");
}
__device__ __forceinline__ void llc_store_f32x4(float* p, f32x4 v) {
  asm volatile("global_store_dwordx4 %0, %1, off sc0 sc1" :: "v"(p), "v"(v) : "memory");
}
__device__ __forceinline__ f32x4 llc_load_f32x4(const float* p) {
  f32x4 r;
  asm volatile("global_load_dwordx4 %0, %1, off sc0 sc1" : "=&v"(r) : "v"(p) : "memory");
  return r;
}

// ---------- stage A: xg[row][d*1024+g] = emb[wid[row]] . Wih_d[g] + b_d[g] ----------
// 128x128 block, 8x8 per-thread tile, register-prefetch software pipeline.
// Epilogue: grid-stride sentinel fill of h_all.
#define XBM 128
#define XBN 128
#define XBK 20
__global__ __launch_bounds__(256) void xproj_kernel(
    const int*   __restrict__ wid,    // [NTOK]
    const float* __restrict__ emb,    // [V][300]
    const float* __restrict__ wih_f,  // [1024][300]
    const float* __restrict__ wih_b,
    const float* __restrict__ b_f,
    const float* __restrict__ b_b,
    float* __restrict__ xg,           // [NTOK][2048]
    float*       h_all,               // sentinel-fill target
    int          n4)                  // h_all size in f32x4
{
  __shared__ float Ast[XBK][XBM];    // [k][m]  10 KB
  __shared__ float Bst[XBK][XBN];    // [k][n]  10 KB
  __shared__ int   wid_s[XBM];

  const int tid = threadIdx.x;
  const int m0 = blockIdx.y * XBM;
  const int n0 = blockIdx.x * XBN;   // 0..2047 in steps of 128
  const int d  = n0 >> 10;
  const float* wih  = d ? wih_b : wih_f;
  const float* bias = d ? b_b  : b_f;
  const int g0 = n0 & 1023;

  if (tid < XBM) wid_s[tid] = wid[m0 + tid];
  __syncthreads();

  const int srow = tid & 127;
  const int half = tid >> 7;         // wave-uniform
  const float* sbase = half ? (wih + (size_t)(g0 + srow) * E_)
                            : (emb + (size_t)wid_s[srow] * E_);
  float* sdst = half ? &Bst[0][0] : &Ast[0][0];

  f32x4 pre[5];
#pragma unroll
  for (int qd = 0; qd < 5; ++qd) pre[qd] = *(const f32x4*)(sbase + qd * 4);

  const int tx = tid & 15, ty = tid >> 4;
  float acc[8][8] = {};

  for (int k0 = 0; k0 < 300; k0 += XBK) {
#pragma unroll
    for (int qd = 0; qd < 5; ++qd)
#pragma unroll
      for (int e = 0; e < 4; ++e)
        sdst[(qd * 4 + e) * XBM + srow] = pre[qd][e];
    if (k0 + XBK < 300) {
      const float* p = sbase + k0 + XBK;
#pragma unroll
      for (int qd = 0; qd < 5; ++qd) pre[qd] = *(const f32x4*)(p + qd * 4);
    }
    __syncthreads();

#pragma unroll
    for (int k = 0; k < XBK; ++k) {
      float av[8], bv[8];
      *(f32x4*)&av[0] = *(const f32x4*)&Ast[k][ty * 8];
      *(f32x4*)&av[4] = *(const f32x4*)&Ast[k][ty * 8 + 4];
      *(f32x4*)&bv[0] = *(const f32x4*)&Bst[k][tx * 8];
      *(f32x4*)&bv[4] = *(const f32x4*)&Bst[k][tx * 8 + 4];
#pragma unroll
      for (int i = 0; i < 8; ++i)
#pragma unroll
        for (int j = 0; j < 8; ++j)
          acc[i][j] += av[i] * bv[j];
    }
    __syncthreads();
  }

#pragma unroll
  for (int i = 0; i < 8; ++i) {
    const int r = m0 + ty * 8 + i;
    float* op = xg + (size_t)r * XGLD + n0 + tx * 8;
#pragma unroll
    for (int j = 0; j < 8; ++j)
      op[j] = acc[i][j] + bias[g0 + tx * 8 + j];
  }

  {
    const int blin = blockIdx.y * 16 + blockIdx.x;   // 0..2047
    f32x4 sv = {SENT, SENT, SENT, SENT};
    for (int i = blin * 256 + tid; i < n4; i += 2048 * 256)
      llc_store_f32x4(h_all + (size_t)i * 4, sv);
  }
}

// ---------- stage B: LSTM, 256 blocks, 2-phase batch pipeline (round-12 proven) -----
// Block = (d, q eighth of 4 batches, sl slice of 16 units = 64 gate rows, unit-major).
// Phases: A = batches {0,1}, B = {2,3}. 4-slot schedule per step:
//   slot1 GEMM_A(s) | slot2 reduce_A(s)+pub || spin_B(s-1) || EMIT_A(s-1)[sl0]
//   slot3 GEMM_B(s) | slot4 reduce_B(s)+pub || spin_A(s)   || EMIT_B(s-1)[sl0]
// NEW: sl==0 blocks compute emission partials in otherwise-idle waves 4-7 using
// the full-h already in h_lds; epilogue emits the final step. No barrier changes.
__global__ __launch_bounds__(512, 2) void lstm_kernel(
    const float* __restrict__ xg,     // [NTOK][2048]
    const float* __restrict__ whh_f,  // [1024][256]
    const float* __restrict__ whh_b,  // [1024][256]
    const float* __restrict__ wout,   // [4][512]
    float*       h_all,               // [16 grp][512 t][4 bl][256 j]
    float*       em_part)             // [2 d][32 b][512 t][4 tag]
{
  const int bid = blockIdx.x;        // 0..255
  const int d   = bid >> 7;
  const int q   = (bid >> 4) & 7;    // batch eighth
  const int sl  = bid & 15;          // slice
  const int tid = threadIdx.x;
  const int kp  = tid >> 6;          // 0..7 (wave / k-chunk)
  const int lane = tid & 63;
  const int bl_loc = lane >> 5;      // batch within phase (0/1)
  const int rg  = lane & 31;         // row pair index
  const float* __restrict__ whh = d ? whh_b : whh_f;

  __shared__ float h_lds[4 * 260];           // h[bl][k+pad]             (4.2 KB)
  __shared__ float part_lds[2 * 8 * 2 * 72]; // [ph][kp][bl_loc][row+pad] (9.2 KB)
  __shared__ float wsl_l[1024];              // wout[tag][d*256+j]        (4 KB)

  // ---- per-thread weights: rows rg*2, rg*2+1 (unit-major), k-chunk kp ----
  f32x4 wreg[2][8];
#pragma unroll
  for (int r = 0; r < 2; ++r) {
    const int row_l = rg * 2 + r;            // u*4 + gt
    const int u  = row_l >> 2;
    const int gt = row_l & 3;
    const int grow = gt * 256 + sl * 16 + u;
    const float* rp = whh + (size_t)grow * H_ + kp * 32;
#pragma unroll
    for (int qq = 0; qq < 8; ++qq) wreg[r][qq] = *(const f32x4*)(rp + qq * 4);
  }

  for (int idx = tid; idx < 4 * 260; idx += 512) h_lds[idx] = 0.f;
  for (int idx = tid; idx < 1024; idx += 512)
    wsl_l[idx] = wout[(idx >> 8) * 512 + d * 256 + (idx & 255)];
  __syncthreads();

  float* hgrp = h_all + (size_t)(d * 8 + q) * (L_ * 1024);   // [512 t][4 bl][256 j]

  // reduce-thread state: tid<32 -> phase A (bl 0,1); tid 32..63 -> phase B (bl 2,3)
  const int r_u  = (tid & 31) >> 1;
  const int r_bl = (tid < 32) ? (tid & 1) : (2 + (tid & 1));
  float c = 0.f;
  const float* xbase = xg + ((size_t)(q * 4 + r_bl) * L_) * XGLD + d * 1024 + sl * 16 + r_u;
  float x0 = 0.f, x1 = 0.f, x2 = 0.f, x3 = 0.f;
  if (tid < 64) {
    const int t0 = d ? (L_ - 1) : 0;
    const float* xp = xbase + (size_t)t0 * XGLD;
    x0 = xp[0]; x1 = xp[256]; x2 = xp[512]; x3 = xp[768];
  }

#define GEMM_PHASE(PH, BLBASE)                                                \
  do {                                                                        \
    const int blg = (BLBASE) + bl_loc;                                        \
    const float* hb = &h_lds[blg * 260 + kp * 32];                            \
    float a0 = 0.f, a1 = 0.f;                                                 \
    _Pragma("unroll")                                                         \
    for (int i = 0; i < 8; ++i) {                                             \
      f32x4 hv = *(const f32x4*)(hb + i * 4);                                 \
      a0 += wreg[0][i].x * hv.x + wreg[0][i].y * hv.y                         \
          + wreg[0][i].z * hv.z + wreg[0][i].w * hv.w;                        \
      a1 += wreg[1][i].x * hv.x + wreg[1][i].y * hv.y                         \
          + wreg[1][i].z * hv.z + wreg[1][i].w * hv.w;                        \
    }                                                                         \
    f32x2 pv = {a0, a1};                                                      \
    *(f32x2*)&part_lds[(PH) * 1152 + kp * 144 + bl_loc * 72 + rg * 2] = pv;   \
  } while (0)

#define REDUCE_PUBLISH(PH, TT, TN)                                            \
  do {                                                                        \
    f32x4 g = {x0, x1, x2, x3};                                               \
    _Pragma("unroll")                                                         \
    for (int k2 = 0; k2 < 8; ++k2)                                            \
      g += *(const f32x4*)&part_lds[(PH) * 1152 + k2 * 144                    \
                                    + (tid & 1) * 72 + r_u * 4];              \
    float gi = fsigmoid_(g.x);                                                \
    float gf = fsigmoid_(g.y);                                                \
    float gg = ftanh_(g.z);                                                   \
    float go = fsigmoid_(g.w);                                                \
    c = gf * c + gi * gg;                                                     \
    float h = go * ftanh_(c);                                                 \
    llc_store_f32(&hgrp[(size_t)(TT) * 1024 + r_bl * 256 + sl * 16 + r_u], h);\
    if ((TN) >= 0) {                                                          \
      const float* xp = xbase + (size_t)(TN) * XGLD;                          \
      x0 = xp[0]; x1 = xp[256]; x2 = xp[512]; x3 = xp[768];                   \
    }                                                                         \
  } while (0)

#define SPIN_LOAD(BASETID, BLBASE, TT)                                        \
  do {                                                                        \
    const int i = tid - (BASETID);                                            \
    const int blg = (BLBASE) + (i >> 6);                                      \
    const int j4 = (i & 63) * 4;                                              \
    const float* p0 = hgrp + (size_t)(TT) * 1024 + blg * 256 + j4;            \
    f32x4 v0;                                                                 \
    bool bad;                                                                 \
    do {                                                                      \
      v0 = llc_load_f32x4(p0);                                                \
      asm volatile("s_waitcnt vmcnt(0)" ::: "memory");                        \
      __builtin_amdgcn_sched_barrier(0);                                      \
      bad = (v0.x == SENT) | (v0.y == SENT) | (v0.z == SENT) | (v0.w == SENT);\
    } while (bad);                                                            \
    *(f32x4*)&h_lds[blg * 260 + j4] = v0;                                     \
  } while (0)

// Emission partial for this direction: threads 256..511. e = tag*64 + l;
// l = blp*32 + li; li sums 8 j's, width-32 shfl reduce, li==0 stores.
#define EMIT(BLBASE, TT)                                                      \
  do {                                                                        \
    const int e   = tid - 256;                                                \
    const int tag = e >> 6;                                                   \
    const int l   = e & 63;                                                   \
    const int blp = l >> 5;                                                   \
    const int li  = l & 31;                                                   \
    const int blg = (BLBASE) + blp;                                           \
    float sacc = 0.f;                                                         \
    _Pragma("unroll")                                                         \
    for (int i8 = 0; i8 < 8; ++i8) {                                          \
      const int j = li + 32 * i8;                                             \
      sacc += h_lds[blg * 260 + j] * wsl_l[tag * 256 + j];                    \
    }                                                                         \
    _Pragma("unroll")                                                         \
    for (int m = 1; m < 32; m <<= 1) sacc += __shfl_xor(sacc, m, 64);         \
    if (li == 0)                                                              \
      em_part[(((size_t)d * 32 + q * 4 + blg) * L_ + (TT)) * 4 + tag] = sacc; \
  } while (0)

  for (int s = 0; s < L_; ++s) {
    const int t  = d ? (L_ - 1 - s) : s;
    const int tp = d ? (t + 1) : (t - 1);          // previous step's time index
    const int tn = (s < L_ - 1) ? (d ? (t - 1) : (t + 1)) : -1;

    // ---- slot1: GEMM phase A ----
    GEMM_PHASE(0, 0);
    __syncthreads();

    // ---- slot2: reduce/publish A(s) || spin B(s-1) || emit A(s-1) [sl==0] ----
    if (tid < 32) {
      REDUCE_PUBLISH(0, t, tn);
    } else if (s > 0 && tid >= 64 && tid < 192) {
      SPIN_LOAD(64, 2, tp);
    } else if (sl == 0 && s > 0 && tid >= 256) {
      EMIT(0, tp);
    }
    __syncthreads();

    // ---- slot3: GEMM phase B ----
    GEMM_PHASE(1, 2);
    __syncthreads();

    // ---- slot4: reduce/publish B(s) || spin A(s) || emit B(s-1) [sl==0] ----
    if (tid >= 32 && tid < 64) {
      REDUCE_PUBLISH(1, t, tn);
    } else if (s < L_ - 1 && tid >= 64 && tid < 192) {
      SPIN_LOAD(64, 0, t);
    } else if (sl == 0 && s > 0 && tid >= 256) {
      EMIT(2, tp);
    }
    __syncthreads();
  }

  // ---- epilogue: emit final step (both phases), sl==0 blocks only ----
  if (sl == 0) {
    const int tl = d ? 0 : (L_ - 1);
    if (tid >= 64 && tid < 192) SPIN_LOAD(64, 0, tl);
    else if (tid >= 192 && tid < 320) SPIN_LOAD(192, 2, tl);
    __syncthreads();
    if (tid >= 256) {
      EMIT(0, tl);
      EMIT(2, tl);
    }
  }

#undef GEMM_PHASE
#undef REDUCE_PUBLISH
#undef SPIN_LOAD
#undef EMIT
}

// ---------- Viterbi decode: one block per batch; em = part_f + part_b + bias --------
__global__ __launch_bounds__(64) void viterbi_kernel(
    const float* __restrict__ em_part, // [2][32][512][4]
    const float* __restrict__ bout,    // [4]
    const float* __restrict__ trans,   // [4][4]
    const float* __restrict__ strans,  // [4]
    const float* __restrict__ etrans,  // [4]
    const int*   __restrict__ mask,    // [32][512]
    int* __restrict__ out)             // [32][512]
{
  __shared__ float em_l[512 * 4];
  __shared__ int   msk_l[512];
  __shared__ int   hist_l[512 * 4];
  __shared__ int   tags_l[512];

  const int b = blockIdx.x;
  const int tid = threadIdx.x;
  const float* epf = em_part + ((size_t)(0 + b) * L_) * 4;
  const float* epb = em_part + ((size_t)(32 + b) * L_) * 4;
  const f32x4 bo4 = {bout[0], bout[1], bout[2], bout[3]};

  for (int i = tid; i < 512; i += 64) {
    f32x4 e0 = *(const f32x4*)&epf[i * 4];
    f32x4 e1 = *(const f32x4*)&epb[i * 4];
    *(f32x4*)&em_l[i * 4] = e0 + e1 + bo4;
    msk_l[i] = mask[b * L_ + i];
  }
  __syncthreads();

  if (tid == 0) {
    float tr[4][4];
#pragma unroll
    for (int i = 0; i < 4; ++i)
#pragma unroll
      for (int jj = 0; jj < 4; ++jj) tr[i][jj] = trans[i * 4 + jj];

    float sc[4];
#pragma unroll
    for (int tag = 0; tag < 4; ++tag) sc[tag] = strans[tag] + em_l[tag];

    for (int t = 1; t < L_; ++t) {
      float ns[4];
#pragma unroll
      for (int to = 0; to < 4; ++to) {
        float best = sc[0] + tr[0][to];
        int bf = 0;
#pragma unroll
        for (int fr = 1; fr < 4; ++fr) {
          float v = sc[fr] + tr[fr][to];
          if (v > best) { best = v; bf = fr; }
        }
        ns[to] = best + em_l[t * 4 + to];
        hist_l[t * 4 + to] = bf;
      }
      const int mt = msk_l[t];
#pragma unroll
      for (int to = 0; to < 4; ++to) sc[to] = mt ? ns[to] : sc[to];
    }

#pragma unroll
    for (int tag = 0; tag < 4; ++tag) sc[tag] += etrans[tag];
    int cur = 0;
    float best = sc[0];
#pragma unroll
    for (int i = 1; i < 4; ++i)
      if (sc[i] > best) { best = sc[i]; cur = i; }

    tags_l[L_ - 1] = msk_l[L_ - 1] ? cur : 0;
    for (int t = L_ - 1; t >= 1; --t) {
      if (msk_l[t]) cur = hist_l[t * 4 + cur];
      tags_l[t - 1] = msk_l[t - 1] ? cur : 0;
    }
  }
  __syncthreads();
  for (int i = tid; i < 512; i += 64) out[b * L_ + i] = tags_l[i];
}

extern "C" void kernel_launch(void* const* d_in, const int* in_sizes, int n_in,
                              void* d_out, int out_size, void* d_ws, size_t ws_size,
                              hipStream_t stream) {
  const int*   word_ids = (const int*)d_in[0];
  const int*   mask     = (const int*)d_in[1];
  // d_in[2] label_ids: unused
  const float* emb   = (const float*)d_in[3];
  const float* Wih_f = (const float*)d_in[4];
  const float* Whh_f = (const float*)d_in[5];
  const float* b_f   = (const float*)d_in[6];
  const float* Wih_b = (const float*)d_in[7];
  const float* Whh_b = (const float*)d_in[8];
  const float* b_b   = (const float*)d_in[9];
  const float* W_out = (const float*)d_in[10];
  const float* b_out = (const float*)d_in[11];
  const float* trans = (const float*)d_in[12];
  const float* strans = (const float*)d_in[13];
  const float* etrans = (const float*)d_in[14];
  int* out = (int*)d_out;

  float* xg      = (float*)d_ws;                           // 128 MiB
  float* h_all   = xg + (size_t)NTOK * XGLD;               // 33.5 MiB
  float* em_part = h_all + (size_t)16 * L_ * 1024;         // 512 KiB

  const int n4 = 16 * L_ * 1024 / 4;                       // 2,097,152 f32x4
  xproj_kernel<<<dim3(16, 128), 256, 0, stream>>>(word_ids, emb, Wih_f, Wih_b,
                                                  b_f, b_b, xg, h_all, n4);
  lstm_kernel<<<256, 512, 0, stream>>>(xg, Whh_f, Whh_b, W_out, h_all, em_part);
  viterbi_kernel<<<32, 64, 0, stream>>>(em_part, b_out, trans, strans, etrans,
                                        mask, out);
}